// Round 12
// baseline (677.462 us; speedup 1.0000x reference)
//
#include <hip/hip_runtime.h>
#include <hip/hip_bf16.h>
#include <stdint.h>

// ---------------------------------------------------------------------------
// Problem constants
// ---------------------------------------------------------------------------
#define NCLS   6
#define NATOMS 5
#define B_     64
#define P_     196
#define D_     768
#define H_     3072
#define SEQ    (NCLS + P_)        // 202
#define NPATCH (B_ * P_)          // 12544
#define NPAIR  (B_ * NCLS)        // 384

typedef unsigned short ushort_t;
typedef __attribute__((ext_vector_type(8))) short  bf16x8;
typedef __attribute__((ext_vector_type(4))) float  f32x4;

// ---------------------------------------------------------------------------
// Helpers
// ---------------------------------------------------------------------------
// fast tanh-form GELU (max abs err ~1e-3; threshold budget 3.98e-2)
__device__ __forceinline__ float gelu_fast(float x) {
    float x2 = x * x;
    float y  = x * (1.59576912f + 0.07135482f * x2);
    float e  = __expf(y);
    return x * e / (e + 1.0f);
}

__device__ __forceinline__ ushort_t f2bf(float f) {
    uint32_t u = __builtin_bit_cast(uint32_t, f);
    u = (u + 0x7fffu + ((u >> 16) & 1u)) >> 16;
    return (ushort_t)u;
}

__device__ __forceinline__ void gload16(const ushort_t* g, ushort_t* l) {
    __builtin_amdgcn_global_load_lds(
        (const __attribute__((address_space(1))) uint32_t*)g,
        (__attribute__((address_space(3))) uint32_t*)l,
        16, 0, 0);
}

// ---------------------------------------------------------------------------
// prep kernel: fp32->bf16 for the 4 weight tensors + x split (one launch)
// ---------------------------------------------------------------------------
#define CVT_B1 (H_ * D_ / 1024)              // w1
#define CVT_B2 (CVT_B1 + D_ * H_ / 1024)     // + w2
#define CVT_B3 (CVT_B2 + NATOMS * H_ * D_ / 1024)
#define CVT_B4 (CVT_B3 + NATOMS * D_ * H_ / 1024)
#define PREP_NB (CVT_B4 + B_ * SEQ * D_ / 1024)

__global__ void prep_kernel(const float* __restrict__ w1, ushort_t* __restrict__ o1,
                            const float* __restrict__ w2, ushort_t* __restrict__ o2,
                            const float* __restrict__ aiw, ushort_t* __restrict__ o3,
                            const float* __restrict__ aow, ushort_t* __restrict__ o4,
                            const float* __restrict__ x, ushort_t* __restrict__ xp,
                            ushort_t* __restrict__ cls) {
    int bid = blockIdx.x;
    if (bid < CVT_B4) {
        const float* src; ushort_t* dst; int i;
        if (bid < CVT_B1)      { src = w1;  dst = o1; i = bid * 1024; }
        else if (bid < CVT_B2) { src = w2;  dst = o2; i = (bid - CVT_B1) * 1024; }
        else if (bid < CVT_B3) { src = aiw; dst = o3; i = (bid - CVT_B2) * 1024; }
        else                   { src = aow; dst = o4; i = (bid - CVT_B3) * 1024; }
        i += threadIdx.x * 4;
        float4 v = *(const float4*)(src + i);
        ushort4 o;
        o.x = f2bf(v.x); o.y = f2bf(v.y); o.z = f2bf(v.z); o.w = f2bf(v.w);
        *(ushort4*)(dst + i) = o;
    } else {
        int i = (bid - CVT_B4) * 1024 + threadIdx.x * 4;
        int row = i / D_;
        int col = i - row * D_;
        int b = row / SEQ, s = row - b * SEQ;
        float4 v = *(const float4*)(x + i);
        ushort4 o;
        o.x = f2bf(v.x); o.y = f2bf(v.y); o.z = f2bf(v.z); o.w = f2bf(v.w);
        if (s < NCLS) {
            *(ushort4*)(cls + (size_t)(b * NCLS + s) * D_ + col) = o;
        } else {
            *(ushort4*)(xp + (size_t)(b * P_ + (s - NCLS)) * D_ + col) = o;
        }
    }
}

// ---------------------------------------------------------------------------
// Gate
// ---------------------------------------------------------------------------
__global__ void gate_kernel(const float* __restrict__ x, const float* __restrict__ gd,
                            int* __restrict__ src, int* __restrict__ dst,
                            float* __restrict__ wgt) {
    int r = blockIdx.x;
    int b = r / NCLS, n = r - b * NCLS;
    const float* xr = x + (size_t)(b * SEQ + n) * D_;
    const float* g  = gd + (size_t)n * D_;
    int lane = threadIdx.x;
    float s = 0.f;
    for (int k = lane; k < D_; k += 64) s += xr[k] * g[k];
    #pragma unroll
    for (int off = 32; off > 0; off >>= 1) s += __shfl_down(s, off, 64);
    if (lane == 0) {
        float logit = s;
        bool left = (logit >= 0.f);
        float p = 1.f / (1.f + expf(-logit));
        float w = left ? p : (1.f - p);
        const int LK[NCLS] = {3, 4, 8, 9, 13, 14};
        const int RK[NCLS] = {15, 20, 16, 21, 17, 22};
        int key = left ? LK[n] : RK[n];
        src[r] = key / NATOMS;
        dst[r] = key % NATOMS;
        wgt[r] = w;
    }
}

// ===========================================================================
// Shared GEMM building blocks
// ===========================================================================
// stage a [ROWS x 32] bf16 tile; inverse-swizzled global source, linear dest.
template <int ROWS, int NT>
__device__ __forceinline__ void stage_t32(const ushort_t* __restrict__ gpanel, int K,
                                          int kbase, ushort_t* lds, int tid) {
    constexpr int LOADS = ROWS * 4 / NT;
    static_assert(LOADS * NT == ROWS * 4, "stage divisibility");
    #pragma unroll
    for (int l = 0; l < LOADS; ++l) {
        int c = l * NT + tid;
        int row = c >> 2;
        int col = ((c & 3) ^ ((row >> 1) & 3)) << 3;
        gload16(gpanel + (size_t)row * K + kbase + col, lds + ((size_t)c << 3));
    }
}

#define BAR     asm volatile("s_barrier" ::: "memory")
#define VMW(N)  asm volatile("s_waitcnt vmcnt(" #N ")" ::: "memory")
#define VMW_C(VAL) do { \
    if constexpr ((VAL) == 3) { VMW(3); } \
    else if constexpr ((VAL) == 4) { VMW(4); } \
    else if constexpr ((VAL) == 6) { VMW(6); } \
    else { VMW(8); } } while (0)

// ===========================================================================
// gemm32: BK=32 2-phase counted-vmcnt GEMM (GEMM0 config).
// 128x256 tile, 8 waves (2M x 4N -> TRUE 64x64 wave tile: 0.5 ds_read/MFMA,
// 1.5x better than r9's 64x32), LDS 2 x (128+256)x32x2B = 48 KB -> 3 blk/CU
// (24 waves/CU = 6/SIMD: MORE TLP than r9's 16).  Per K32-tile: stage next
// tile (3 gload_lds/thread) -> VMW(3) -> barrier -> 16 MFMA/wave -> barrier.
// L2 cohorts 7m x 3n; swizzle slot^=(row>>1)&3 (0 conflicts, proven).
// ===========================================================================
#define COMPUTE32(DB) do { \
    __builtin_amdgcn_s_setprio(1); \
    bf16x8 bfr[FN]; \
    _Pragma("unroll") \
    for (int f = 0; f < FN; ++f) \
        bfr[f] = *(const bf16x8*)(&LB[DB][bbase + f * 512]); \
    _Pragma("unroll") \
    for (int mh = 0; mh < 2; ++mh) { \
        bf16x8 afr[FMH]; \
        _Pragma("unroll") \
        for (int f = 0; f < FMH; ++f) \
            afr[f] = *(const bf16x8*)(&LA[DB][abase + mh * MH_OFF + f * 512]); \
        _Pragma("unroll") \
        for (int mi = 0; mi < FMH; ++mi) \
            _Pragma("unroll") \
            for (int ni = 0; ni < FN; ++ni) \
                acc[mh * FMH + mi][ni] = __builtin_amdgcn_mfma_f32_16x16x32_bf16( \
                    afr[mi], bfr[ni], acc[mh * FMH + mi][ni], 0, 0, 0); \
    } \
    __builtin_amdgcn_s_setprio(0); \
    __builtin_amdgcn_sched_barrier(0); \
} while (0)

#define STAGE32(T, DB) \
    stage_t32<BM, NT>(Ab, K, ((T) << 5), &LA[DB][0], tid); \
    stage_t32<BN, NT>(Bb, K, ((T) << 5), &LB[DB][0], tid);

template <int MODE, int BM, int BN, int WM, int WN, int MINW>
__global__ __launch_bounds__(WM * WN * 64, MINW)
void gemm32(const ushort_t* __restrict__ A, const ushort_t* __restrict__ Bm,
            int N, int K, int grid_m, int grid_n,
            const float* __restrict__ bias,
            float* __restrict__ outF, ushort_t* __restrict__ outB) {
    constexpr int NT   = WM * WN * 64;
    constexpr int FMH  = BM / (32 * WM);        // 2
    constexpr int FN   = BN / (16 * WN);        // 4
    constexpr int MH_OFF = (BM / WM / 2) * 32;  // 32 rows x 32 cols
    constexpr int VMWN = 4 * (BM + BN) / NT;    // 3

    __shared__ __align__(16) ushort_t LA[2][BM * 32];
    __shared__ __align__(16) ushort_t LB[2][BN * 32];

    // bijective XCD-chunk swizzle (m204) + L2 cohort decode (7m x 3n)
    const int nwg = gridDim.x;
    int bid = blockIdx.x;
    int q = nwg >> 3, r = nwg & 7;
    int xcd = bid & 7, slot = bid >> 3;
    int wg = (xcd < r ? xcd * (q + 1) : r * (q + 1) + (xcd - r) * q) + slot;
    int per_col = (grid_m / 7) * 21;
    int gn = wg / per_col;  int r1 = wg - gn * per_col;
    int gm = r1 / 21;       int ii = r1 - gm * 21;
    int tile_m = gm * 7 + ii / 3;
    int tile_n = gn * 3 + (ii - (ii / 3) * 3);

    const ushort_t* Ab = A  + (size_t)tile_m * BM * K;
    const ushort_t* Bb = Bm + (size_t)tile_n * BN * K;

    const int tid  = threadIdx.x;
    const int lane = tid & 63;
    const int wave = tid >> 6;
    const int wr = wave / WN;
    const int wc = wave % WN;

    const int frow = lane & 15;
    const int fsl  = lane >> 4;
    const int rbase = frow * 32 + ((fsl ^ ((frow >> 1) & 3)) << 3);
    const int abase = wr * ((BM / WM) * 32) + rbase;
    const int bbase = wc * ((BN / WN) * 32) + rbase;

    f32x4 acc[2 * FMH][FN];
    #pragma unroll
    for (int i = 0; i < 2 * FMH; i++)
        #pragma unroll
        for (int j = 0; j < FN; j++)
            acc[i][j] = (f32x4){0.f, 0.f, 0.f, 0.f};

    const int nkt = K >> 5;   // 24 (K=768) or 96 (K=3072): even

    STAGE32(0, 0)
    for (int tb = 0; tb < (nkt >> 1) - 1; ++tb) {
        STAGE32(2 * tb + 1, 1)
        VMW_C(VMWN); BAR;
        COMPUTE32(0);
        BAR;
        STAGE32(2 * tb + 2, 0)
        VMW_C(VMWN); BAR;
        COMPUTE32(1);
        BAR;
    }
    STAGE32(nkt - 1, 1)
    VMW_C(VMWN); BAR;
    COMPUTE32(0);
    BAR;
    VMW(0); BAR;
    COMPUTE32(1);

    // epilogue: C/D layout col = lane&15, row = (lane>>4)*4 + reg
    const int fq = lane >> 4;
    #pragma unroll
    for (int mi = 0; mi < 2 * FMH; mi++) {
        #pragma unroll
        for (int ni = 0; ni < FN; ni++) {
            int n = tile_n * BN + wc * (BN / WN) + ni * 16 + frow;
            float bn = bias[n];
            #pragma unroll
            for (int rr = 0; rr < 4; rr++) {
                int m = tile_m * BM + wr * (BM / WM) + mi * 16 + fq * 4 + rr;
                float v = acc[mi][ni][rr];
                if constexpr (MODE == 0) {
                    outB[(size_t)m * N + n] = f2bf(gelu_fast(v + bn));
                } else {
                    int b = m / P_, p = m - b * P_;
                    outF[(size_t)(b * SEQ + NCLS + p) * D_ + n] = v + bn;
                }
            }
        }
    }
}

// ===========================================================================
// gemm2s: r9-exact BK=64 2-phase kernel (GEMM1 control; proven 105us)
// ===========================================================================
#define STAGE64T(T, DB) \
    stage_t32<BM, NT>(Ab, K, ((T) << 6),      &LA[DB][0][0], tid); \
    stage_t32<BN, NT>(Bb, K, ((T) << 6),      &LB[DB][0][0], tid); \
    stage_t32<BM, NT>(Ab, K, ((T) << 6) + 32, &LA[DB][1][0], tid); \
    stage_t32<BN, NT>(Bb, K, ((T) << 6) + 32, &LB[DB][1][0], tid);

#define COMPUTE64(DB) do { \
    __builtin_amdgcn_s_setprio(1); \
    _Pragma("unroll") \
    for (int ks = 0; ks < 2; ++ks) { \
        bf16x8 bfr[FN]; \
        _Pragma("unroll") \
        for (int f = 0; f < FN; ++f) \
            bfr[f] = *(const bf16x8*)(&LB[DB][ks][bbase + f * 512]); \
        _Pragma("unroll") \
        for (int mh = 0; mh < 2; ++mh) { \
            bf16x8 afr[FMH]; \
            _Pragma("unroll") \
            for (int f = 0; f < FMH; ++f) \
                afr[f] = *(const bf16x8*)(&LA[DB][ks][abase + mh * MH_OFF + f * 512]); \
            _Pragma("unroll") \
            for (int mi = 0; mi < FMH; ++mi) \
                _Pragma("unroll") \
                for (int ni = 0; ni < FN; ++ni) \
                    acc[mh * FMH + mi][ni] = __builtin_amdgcn_mfma_f32_16x16x32_bf16( \
                        afr[mi], bfr[ni], acc[mh * FMH + mi][ni], 0, 0, 0); \
        } \
    } \
    __builtin_amdgcn_s_setprio(0); \
    __builtin_amdgcn_sched_barrier(0); \
} while (0)

template <int MODE, int BM, int BN, int WM, int WN, int MINW>
__global__ __launch_bounds__(WM * WN * 64, MINW)
void gemm2s(const ushort_t* __restrict__ A, const ushort_t* __restrict__ Bm,
            int N, int K, int grid_m, int grid_n,
            const float* __restrict__ bias,
            float* __restrict__ outF, ushort_t* __restrict__ outB) {
    constexpr int NT   = WM * WN * 64;
    constexpr int FMH  = BM / (32 * WM);
    constexpr int FN   = BN / (16 * WN);
    constexpr int MH_OFF = (BM / WM / 2) * 32;
    constexpr int VMWN = 8 * (BM + BN) / NT;

    __shared__ __align__(16) ushort_t LA[2][2][BM * 32];
    __shared__ __align__(16) ushort_t LB[2][2][BN * 32];

    const int nwg = gridDim.x;
    int bid = blockIdx.x;
    int q = nwg >> 3, r = nwg & 7;
    int xcd = bid & 7, slot = bid >> 3;
    int wg = (xcd < r ? xcd * (q + 1) : r * (q + 1) + (xcd - r) * q) + slot;
    int per_col = (grid_m / 7) * 21;
    int gn = wg / per_col;  int r1 = wg - gn * per_col;
    int gm = r1 / 21;       int ii = r1 - gm * 21;
    int tile_m = gm * 7 + ii / 3;
    int tile_n = gn * 3 + (ii - (ii / 3) * 3);

    const ushort_t* Ab = A  + (size_t)tile_m * BM * K;
    const ushort_t* Bb = Bm + (size_t)tile_n * BN * K;

    const int tid  = threadIdx.x;
    const int lane = tid & 63;
    const int wave = tid >> 6;
    const int wr = wave / WN;
    const int wc = wave % WN;

    const int frow = lane & 15;
    const int fsl  = lane >> 4;
    const int rbase = frow * 32 + ((fsl ^ ((frow >> 1) & 3)) << 3);
    const int abase = wr * ((BM / WM) * 32) + rbase;
    const int bbase = wc * ((BN / WN) * 32) + rbase;

    f32x4 acc[2 * FMH][FN];
    #pragma unroll
    for (int i = 0; i < 2 * FMH; i++)
        #pragma unroll
        for (int j = 0; j < FN; j++)
            acc[i][j] = (f32x4){0.f, 0.f, 0.f, 0.f};

    const int nkt = K >> 6;

    STAGE64T(0, 0)
    for (int tb = 0; tb < (nkt >> 1) - 1; ++tb) {
        STAGE64T(2 * tb + 1, 1)
        VMW_C(VMWN); BAR;
        COMPUTE64(0);
        BAR;
        STAGE64T(2 * tb + 2, 0)
        VMW_C(VMWN); BAR;
        COMPUTE64(1);
        BAR;
    }
    STAGE64T(nkt - 1, 1)
    VMW_C(VMWN); BAR;
    COMPUTE64(0);
    BAR;
    VMW(0); BAR;
    COMPUTE64(1);

    const int fq = lane >> 4;
    #pragma unroll
    for (int mi = 0; mi < 2 * FMH; mi++) {
        #pragma unroll
        for (int ni = 0; ni < FN; ni++) {
            int n = tile_n * BN + wc * (BN / WN) + ni * 16 + frow;
            float bn = bias[n];
            #pragma unroll
            for (int rr = 0; rr < 4; rr++) {
                int m = tile_m * BM + wr * (BM / WM) + mi * 16 + fq * 4 + rr;
                float v = acc[mi][ni][rr];
                if constexpr (MODE == 0) {
                    outB[(size_t)m * N + n] = f2bf(gelu_fast(v + bn));
                } else {
                    int b = m / P_, p = m - b * P_;
                    outF[(size_t)(b * SEQ + NCLS + p) * D_ + n] = v + bn;
                }
            }
        }
    }
}

// ---------------------------------------------------------------------------
// cls-path GEMM: round-3 2-phase double-buffered structure (proven), BK=64.
// (Underfilled-latency regime: dense 5-atom compute w/ masked scatter.)
// ---------------------------------------------------------------------------
template <int ROWS, int NT>
__device__ __forceinline__ void stage64(const ushort_t* __restrict__ gbase, int K,
                                        int k0, ushort_t* lds, int tid) {
    constexpr int LOADS = ROWS * 64 * 2 / (NT * 16);
    #pragma unroll
    for (int l = 0; l < LOADS; ++l) {
        int c = l * NT + tid;
        gload16(gbase + (size_t)(c >> 3) * K + k0 + ((c & 7) << 3),
                lds + (size_t)c * 8);
    }
}

template <int FM, int FN>
__device__ __forceinline__ void compute64c(const ushort_t* sA, const ushort_t* sB,
                                           int arow0, int brow0, int lane,
                                           f32x4 (&acc)[FM][FN]) {
    const int frow = lane & 15;
    const int fcol = (lane >> 4) * 8;
    #pragma unroll
    for (int ks = 0; ks < 2; ++ks) {
        bf16x8 af[FM], bfv[FN];
        #pragma unroll
        for (int mi = 0; mi < FM; ++mi)
            af[mi] = *(const bf16x8*)(sA + (size_t)(arow0 + mi * 16 + frow) * 64 + ks * 32 + fcol);
        #pragma unroll
        for (int ni = 0; ni < FN; ++ni)
            bfv[ni] = *(const bf16x8*)(sB + (size_t)(brow0 + ni * 16 + frow) * 64 + ks * 32 + fcol);
        #pragma unroll
        for (int mi = 0; mi < FM; ++mi)
            #pragma unroll
            for (int ni = 0; ni < FN; ++ni)
                acc[mi][ni] = __builtin_amdgcn_mfma_f32_16x16x32_bf16(
                    af[mi], bfv[ni], acc[mi][ni], 0, 0, 0);
    }
}

// MODE 2: if src[m]==atom: HID = bf16(gelu(acc + bias[atom*H_+n]))
// MODE 3: if dst[m]==atom: out[(b*SEQ+nn)*D_+n] = (acc + bias[atom*D_+n])*wgt[m]
template <int MODE, int BMc, int BNc, int WM, int WN>
__global__ __launch_bounds__(WM * WN * 64, 2)
void gemm2p(const ushort_t* __restrict__ A,
            const ushort_t* __restrict__ Bm,
            int N, int K, int grid_n,
            const float* __restrict__ bias,
            float* __restrict__ outF,
            ushort_t* __restrict__ outB,
            const int* __restrict__ selIdx,
            const float* __restrict__ wgt) {
    constexpr int NT = WM * WN * 64;
    constexpr int FM = BMc / WM / 16;
    constexpr int FN = BNc / WN / 16;

    __shared__ __align__(16) ushort_t A0[BMc * 64], A1[BMc * 64];
    __shared__ __align__(16) ushort_t B0[BNc * 64], B1[BNc * 64];

    const int nwg = gridDim.x;
    int bid = blockIdx.x;
    int q = nwg >> 3, r = nwg & 7;
    int xcd = bid & 7, slot = bid >> 3;
    int wg = (xcd < r ? xcd * (q + 1) : r * (q + 1) + (xcd - r) * q) + slot;
    int tile_m = wg / grid_n;
    int tile_n = wg - tile_m * grid_n;
    const int atom = blockIdx.z;

    const ushort_t* Ab = A  + (size_t)tile_m * BMc * K;
    const ushort_t* Bb = Bm + ((size_t)atom * N + (size_t)tile_n * BNc) * K;

    const int tid  = threadIdx.x;
    const int lane = tid & 63;
    const int wave = tid >> 6;
    const int arow0 = (wave / WN) * (BMc / WM);
    const int brow0 = (wave % WN) * (BNc / WN);

    f32x4 acc[FM][FN];
    #pragma unroll
    for (int i = 0; i < FM; i++)
        #pragma unroll
        for (int j = 0; j < FN; j++)
            acc[i][j] = (f32x4){0.f, 0.f, 0.f, 0.f};

    const int nkt = K >> 6;

    stage64<BMc, NT>(Ab, K, 0, A0, tid);
    stage64<BNc, NT>(Bb, K, 0, B0, tid);
    asm volatile("s_waitcnt vmcnt(0)" ::: "memory");
    __syncthreads();

    for (int t = 0; t < nkt; t += 2) {
        stage64<BMc, NT>(Ab, K, (t + 1) << 6, A1, tid);
        stage64<BNc, NT>(Bb, K, (t + 1) << 6, B1, tid);
        compute64c<FM, FN>(A0, B0, arow0, brow0, lane, acc);
        asm volatile("s_waitcnt vmcnt(0)" ::: "memory");
        __syncthreads();
        if (t + 2 < nkt) {
            stage64<BMc, NT>(Ab, K, (t + 2) << 6, A0, tid);
            stage64<BNc, NT>(Bb, K, (t + 2) << 6, B0, tid);
        }
        compute64c<FM, FN>(A1, B1, arow0, brow0, lane, acc);
        asm volatile("s_waitcnt vmcnt(0)" ::: "memory");
        __syncthreads();
    }

    const int frow = lane & 15;
    const int fq   = lane >> 4;
    #pragma unroll
    for (int mi = 0; mi < FM; mi++) {
        #pragma unroll
        for (int ni = 0; ni < FN; ni++) {
            int n = tile_n * BNc + brow0 + ni * 16 + frow;
            float bn;
            if constexpr (MODE == 2) bn = bias[atom * H_ + n];
            else                     bn = bias[atom * D_ + n];
            #pragma unroll
            for (int rr = 0; rr < 4; rr++) {
                int m = tile_m * BMc + arow0 + mi * 16 + fq * 4 + rr;
                float v = acc[mi][ni][rr];
                if constexpr (MODE == 2) {
                    if (selIdx[m] == atom)
                        outB[(size_t)m * N + n] = f2bf(gelu_fast(v + bn));
                } else { // MODE 3
                    if (selIdx[m] == atom) {
                        int b = m / NCLS, nn = m - b * NCLS;
                        outF[(size_t)(b * SEQ + nn) * D_ + n] = (v + bn) * wgt[m];
                    }
                }
            }
        }
    }
}

// ---------------------------------------------------------------------------
// Launch
// ---------------------------------------------------------------------------
extern "C" void kernel_launch(void* const* d_in, const int* in_sizes, int n_in,
                              void* d_out, int out_size, void* d_ws, size_t ws_size,
                              hipStream_t stream) {
    const float* x   = (const float*)d_in[0];
    const float* w1  = (const float*)d_in[1];
    const float* b1  = (const float*)d_in[2];
    const float* w2  = (const float*)d_in[3];
    const float* b2  = (const float*)d_in[4];
    const float* gd  = (const float*)d_in[5];
    const float* aiw = (const float*)d_in[6];
    const float* aib = (const float*)d_in[7];
    const float* aow = (const float*)d_in[8];
    const float* aob = (const float*)d_in[9];
    float* out = (float*)d_out;

    char* ws = (char*)d_ws;
    ushort_t* Xp   = (ushort_t*)ws; ws += (size_t)NPATCH * D_ * 2;
    ushort_t* W1b  = (ushort_t*)ws; ws += (size_t)H_ * D_ * 2;
    ushort_t* W2b  = (ushort_t*)ws; ws += (size_t)D_ * H_ * 2;
    ushort_t* H1   = (ushort_t*)ws; ws += (size_t)NPATCH * H_ * 2;
    ushort_t* CLSb = (ushort_t*)ws; ws += (size_t)NPAIR * D_ * 2;
    ushort_t* AIWb = (ushort_t*)ws; ws += (size_t)NATOMS * H_ * D_ * 2;
    ushort_t* AOWb = (ushort_t*)ws; ws += (size_t)NATOMS * D_ * H_ * 2;
    ushort_t* HID  = (ushort_t*)ws; ws += (size_t)NPAIR * H_ * 2;
    int*   SRC = (int*)ws;   ws += NPAIR * 4;
    int*   DST = (int*)ws;   ws += NPAIR * 4;
    float* WGT = (float*)ws; ws += NPAIR * 4;

    // prep: all fp32->bf16 conversions + x split in one launch
    prep_kernel<<<PREP_NB, 256, 0, stream>>>(w1, W1b, w2, W2b, aiw, AIWb, aow, AOWb,
                                             x, Xp, CLSb);
    gate_kernel<<<NPAIR, 64, 0, stream>>>(x, gd, SRC, DST, WGT);

    // GEMM0: NEW 128x256 / BK=32 / 8 waves (64x64 wave tile) / 48KB -> 3 blk/CU
    gemm32<0, 128, 256, 2, 4, 6><<<dim3(1176, 1, 1), 512, 0, stream>>>(
        Xp, W1b, H_, D_, 98, 12, b1, nullptr, H1);
    // GEMM1: r9-exact control (128x128 / BK=64 / 8 waves / 64KB -> 2 blk/CU)
    gemm2s<1, 128, 128, 2, 4, 4><<<dim3(588, 1, 1), 512, 0, stream>>>(
        H1, W2b, D_, H_, 98, 6, b2, out, nullptr);

    // cls path: dense all-atom GEMMs with masked epilogue scatter
    gemm2p<2, 64, 128, 1, 2><<<dim3(NPAIR / 64 * (H_ / 128), 1, NATOMS), 128, 0, stream>>>(
        CLSb, AIWb, H_, D_, H_ / 128, aib, nullptr, HID, SRC, nullptr);
    gemm2p<3, 64, 128, 1, 2><<<dim3(NPAIR / 64 * (D_ / 128), 1, NATOMS), 128, 0, stream>>>(
        HID, AOWb, D_, H_, D_ / 128, aob, out, nullptr, DST, WGT);
}

// Round 13
// 296.485 us; speedup vs baseline: 2.2850x; 2.2850x over previous
//
#include <hip/hip_runtime.h>
#include <hip/hip_bf16.h>
#include <stdint.h>

// ---------------------------------------------------------------------------
// Problem constants
// ---------------------------------------------------------------------------
#define NCLS   6
#define NATOMS 5
#define B_     64
#define P_     196
#define D_     768
#define H_     3072
#define SEQ    (NCLS + P_)        // 202
#define NPATCH (B_ * P_)          // 12544
#define NPAIR  (B_ * NCLS)        // 384

typedef unsigned short ushort_t;
typedef __attribute__((ext_vector_type(8))) short  bf16x8;
typedef __attribute__((ext_vector_type(4))) float  f32x4;

// ---------------------------------------------------------------------------
// Helpers
// ---------------------------------------------------------------------------
// fast tanh-form GELU (max abs err ~1e-3; threshold budget 3.98e-2)
__device__ __forceinline__ float gelu_fast(float x) {
    float x2 = x * x;
    float y  = x * (1.59576912f + 0.07135482f * x2);
    float e  = __expf(y);
    return x * e / (e + 1.0f);
}

__device__ __forceinline__ ushort_t f2bf(float f) {
    uint32_t u = __builtin_bit_cast(uint32_t, f);
    u = (u + 0x7fffu + ((u >> 16) & 1u)) >> 16;
    return (ushort_t)u;
}

__device__ __forceinline__ void gload16(const ushort_t* g, ushort_t* l) {
    __builtin_amdgcn_global_load_lds(
        (const __attribute__((address_space(1))) uint32_t*)g,
        (__attribute__((address_space(3))) uint32_t*)l,
        16, 0, 0);
}

// ---------------------------------------------------------------------------
// prep kernel: fp32->bf16 for the 4 weight tensors + x split (one launch)
// ---------------------------------------------------------------------------
#define CVT_B1 (H_ * D_ / 1024)              // w1
#define CVT_B2 (CVT_B1 + D_ * H_ / 1024)     // + w2
#define CVT_B3 (CVT_B2 + NATOMS * H_ * D_ / 1024)
#define CVT_B4 (CVT_B3 + NATOMS * D_ * H_ / 1024)
#define PREP_NB (CVT_B4 + B_ * SEQ * D_ / 1024)

__global__ void prep_kernel(const float* __restrict__ w1, ushort_t* __restrict__ o1,
                            const float* __restrict__ w2, ushort_t* __restrict__ o2,
                            const float* __restrict__ aiw, ushort_t* __restrict__ o3,
                            const float* __restrict__ aow, ushort_t* __restrict__ o4,
                            const float* __restrict__ x, ushort_t* __restrict__ xp,
                            ushort_t* __restrict__ cls) {
    int bid = blockIdx.x;
    if (bid < CVT_B4) {
        const float* src; ushort_t* dst; int i;
        if (bid < CVT_B1)      { src = w1;  dst = o1; i = bid * 1024; }
        else if (bid < CVT_B2) { src = w2;  dst = o2; i = (bid - CVT_B1) * 1024; }
        else if (bid < CVT_B3) { src = aiw; dst = o3; i = (bid - CVT_B2) * 1024; }
        else                   { src = aow; dst = o4; i = (bid - CVT_B3) * 1024; }
        i += threadIdx.x * 4;
        float4 v = *(const float4*)(src + i);
        ushort4 o;
        o.x = f2bf(v.x); o.y = f2bf(v.y); o.z = f2bf(v.z); o.w = f2bf(v.w);
        *(ushort4*)(dst + i) = o;
    } else {
        int i = (bid - CVT_B4) * 1024 + threadIdx.x * 4;
        int row = i / D_;
        int col = i - row * D_;
        int b = row / SEQ, s = row - b * SEQ;
        float4 v = *(const float4*)(x + i);
        ushort4 o;
        o.x = f2bf(v.x); o.y = f2bf(v.y); o.z = f2bf(v.z); o.w = f2bf(v.w);
        if (s < NCLS) {
            *(ushort4*)(cls + (size_t)(b * NCLS + s) * D_ + col) = o;
        } else {
            *(ushort4*)(xp + (size_t)(b * P_ + (s - NCLS)) * D_ + col) = o;
        }
    }
}

// ---------------------------------------------------------------------------
// Gate
// ---------------------------------------------------------------------------
__global__ void gate_kernel(const float* __restrict__ x, const float* __restrict__ gd,
                            int* __restrict__ src, int* __restrict__ dst,
                            float* __restrict__ wgt) {
    int r = blockIdx.x;
    int b = r / NCLS, n = r - b * NCLS;
    const float* xr = x + (size_t)(b * SEQ + n) * D_;
    const float* g  = gd + (size_t)n * D_;
    int lane = threadIdx.x;
    float s = 0.f;
    for (int k = lane; k < D_; k += 64) s += xr[k] * g[k];
    #pragma unroll
    for (int off = 32; off > 0; off >>= 1) s += __shfl_down(s, off, 64);
    if (lane == 0) {
        float logit = s;
        bool left = (logit >= 0.f);
        float p = 1.f / (1.f + expf(-logit));
        float w = left ? p : (1.f - p);
        const int LK[NCLS] = {3, 4, 8, 9, 13, 14};
        const int RK[NCLS] = {15, 20, 16, 21, 17, 22};
        int key = left ? LK[n] : RK[n];
        src[r] = key / NATOMS;
        dst[r] = key % NATOMS;
        wgt[r] = w;
    }
}

// ===========================================================================
// Shared GEMM building blocks
// ===========================================================================
// stage a [ROWS x 32] bf16 tile; inverse-swizzled global source, linear dest.
template <int ROWS, int NT>
__device__ __forceinline__ void stage_t32(const ushort_t* __restrict__ gpanel, int K,
                                          int kbase, ushort_t* lds, int tid) {
    constexpr int LOADS = ROWS * 4 / NT;
    static_assert(LOADS * NT == ROWS * 4, "stage divisibility");
    #pragma unroll
    for (int l = 0; l < LOADS; ++l) {
        int c = l * NT + tid;
        int row = c >> 2;
        int col = ((c & 3) ^ ((row >> 1) & 3)) << 3;
        gload16(gpanel + (size_t)row * K + kbase + col, lds + ((size_t)c << 3));
    }
}

#define BAR     asm volatile("s_barrier" ::: "memory")
#define VMW(N)  asm volatile("s_waitcnt vmcnt(" #N ")" ::: "memory")
#define VMW_C(VAL) do { \
    if constexpr ((VAL) == 3) { VMW(3); } \
    else if constexpr ((VAL) == 4) { VMW(4); } \
    else if constexpr ((VAL) == 6) { VMW(6); } \
    else { VMW(8); } } while (0)

// ===========================================================================
// gemm32: BK=32 2-phase counted-vmcnt GEMM (GEMM0).
// 128x256 tile, 8 waves (2M x 4N -> 64x64 wave tile: 0.5 ds_read/MFMA,
// 1.5x less LDS traffic than r9's 64x32), LDS 48 KB.
// r12 FIX: MINW=4 (2 blk/CU, 4 waves/SIMD, 128-VGPR budget).  r12's MINW=6
// demanded 6 waves/SIMD -> 85-VGPR cap -> accumulator spill to scratch
// (VGPR_Count 40, WRITE_SIZE 1.39 GB, 677us).  64x64 wave tiles REQUIRE the
// 128-VGPR budget; 3 blk/CU is infeasible with this tile shape.
// Per K32-tile: stage next tile (3 gload_lds/thread) -> VMW(3) -> barrier ->
// 16 MFMA/wave -> barrier.  L2 cohorts 7m x 3n; swizzle slot^=(row>>1)&3.
// ===========================================================================
#define COMPUTE32(DB) do { \
    __builtin_amdgcn_s_setprio(1); \
    bf16x8 bfr[FN]; \
    _Pragma("unroll") \
    for (int f = 0; f < FN; ++f) \
        bfr[f] = *(const bf16x8*)(&LB[DB][bbase + f * 512]); \
    _Pragma("unroll") \
    for (int mh = 0; mh < 2; ++mh) { \
        bf16x8 afr[FMH]; \
        _Pragma("unroll") \
        for (int f = 0; f < FMH; ++f) \
            afr[f] = *(const bf16x8*)(&LA[DB][abase + mh * MH_OFF + f * 512]); \
        _Pragma("unroll") \
        for (int mi = 0; mi < FMH; ++mi) \
            _Pragma("unroll") \
            for (int ni = 0; ni < FN; ++ni) \
                acc[mh * FMH + mi][ni] = __builtin_amdgcn_mfma_f32_16x16x32_bf16( \
                    afr[mi], bfr[ni], acc[mh * FMH + mi][ni], 0, 0, 0); \
    } \
    __builtin_amdgcn_s_setprio(0); \
    __builtin_amdgcn_sched_barrier(0); \
} while (0)

#define STAGE32(T, DB) \
    stage_t32<BM, NT>(Ab, K, ((T) << 5), &LA[DB][0], tid); \
    stage_t32<BN, NT>(Bb, K, ((T) << 5), &LB[DB][0], tid);

template <int MODE, int BM, int BN, int WM, int WN, int MINW>
__global__ __launch_bounds__(WM * WN * 64, MINW)
void gemm32(const ushort_t* __restrict__ A, const ushort_t* __restrict__ Bm,
            int N, int K, int grid_m, int grid_n,
            const float* __restrict__ bias,
            float* __restrict__ outF, ushort_t* __restrict__ outB) {
    constexpr int NT   = WM * WN * 64;
    constexpr int FMH  = BM / (32 * WM);        // 2
    constexpr int FN   = BN / (16 * WN);        // 4
    constexpr int MH_OFF = (BM / WM / 2) * 32;  // 32 rows x 32 cols
    constexpr int VMWN = 4 * (BM + BN) / NT;    // 3

    __shared__ __align__(16) ushort_t LA[2][BM * 32];
    __shared__ __align__(16) ushort_t LB[2][BN * 32];

    // bijective XCD-chunk swizzle (m204) + L2 cohort decode (7m x 3n)
    const int nwg = gridDim.x;
    int bid = blockIdx.x;
    int q = nwg >> 3, r = nwg & 7;
    int xcd = bid & 7, slot = bid >> 3;
    int wg = (xcd < r ? xcd * (q + 1) : r * (q + 1) + (xcd - r) * q) + slot;
    int per_col = (grid_m / 7) * 21;
    int gn = wg / per_col;  int r1 = wg - gn * per_col;
    int gm = r1 / 21;       int ii = r1 - gm * 21;
    int tile_m = gm * 7 + ii / 3;
    int tile_n = gn * 3 + (ii - (ii / 3) * 3);

    const ushort_t* Ab = A  + (size_t)tile_m * BM * K;
    const ushort_t* Bb = Bm + (size_t)tile_n * BN * K;

    const int tid  = threadIdx.x;
    const int lane = tid & 63;
    const int wave = tid >> 6;
    const int wr = wave / WN;
    const int wc = wave % WN;

    const int frow = lane & 15;
    const int fsl  = lane >> 4;
    const int rbase = frow * 32 + ((fsl ^ ((frow >> 1) & 3)) << 3);
    const int abase = wr * ((BM / WM) * 32) + rbase;
    const int bbase = wc * ((BN / WN) * 32) + rbase;

    f32x4 acc[2 * FMH][FN];
    #pragma unroll
    for (int i = 0; i < 2 * FMH; i++)
        #pragma unroll
        for (int j = 0; j < FN; j++)
            acc[i][j] = (f32x4){0.f, 0.f, 0.f, 0.f};

    const int nkt = K >> 5;   // 24 (K=768): even

    STAGE32(0, 0)
    for (int tb = 0; tb < (nkt >> 1) - 1; ++tb) {
        STAGE32(2 * tb + 1, 1)
        VMW_C(VMWN); BAR;
        COMPUTE32(0);
        BAR;
        STAGE32(2 * tb + 2, 0)
        VMW_C(VMWN); BAR;
        COMPUTE32(1);
        BAR;
    }
    STAGE32(nkt - 1, 1)
    VMW_C(VMWN); BAR;
    COMPUTE32(0);
    BAR;
    VMW(0); BAR;
    COMPUTE32(1);

    // epilogue: C/D layout col = lane&15, row = (lane>>4)*4 + reg
    const int fq = lane >> 4;
    #pragma unroll
    for (int mi = 0; mi < 2 * FMH; mi++) {
        #pragma unroll
        for (int ni = 0; ni < FN; ni++) {
            int n = tile_n * BN + wc * (BN / WN) + ni * 16 + frow;
            float bn = bias[n];
            #pragma unroll
            for (int rr = 0; rr < 4; rr++) {
                int m = tile_m * BM + wr * (BM / WM) + mi * 16 + fq * 4 + rr;
                float v = acc[mi][ni][rr];
                if constexpr (MODE == 0) {
                    outB[(size_t)m * N + n] = f2bf(gelu_fast(v + bn));
                } else {
                    int b = m / P_, p = m - b * P_;
                    outF[(size_t)(b * SEQ + NCLS + p) * D_ + n] = v + bn;
                }
            }
        }
    }
}

// ===========================================================================
// gemm2s: r9-exact BK=64 2-phase kernel (GEMM1; proven 105us)
// ===========================================================================
#define STAGE64T(T, DB) \
    stage_t32<BM, NT>(Ab, K, ((T) << 6),      &LA[DB][0][0], tid); \
    stage_t32<BN, NT>(Bb, K, ((T) << 6),      &LB[DB][0][0], tid); \
    stage_t32<BM, NT>(Ab, K, ((T) << 6) + 32, &LA[DB][1][0], tid); \
    stage_t32<BN, NT>(Bb, K, ((T) << 6) + 32, &LB[DB][1][0], tid);

#define COMPUTE64(DB) do { \
    __builtin_amdgcn_s_setprio(1); \
    _Pragma("unroll") \
    for (int ks = 0; ks < 2; ++ks) { \
        bf16x8 bfr[FN]; \
        _Pragma("unroll") \
        for (int f = 0; f < FN; ++f) \
            bfr[f] = *(const bf16x8*)(&LB[DB][ks][bbase + f * 512]); \
        _Pragma("unroll") \
        for (int mh = 0; mh < 2; ++mh) { \
            bf16x8 afr[FMH]; \
            _Pragma("unroll") \
            for (int f = 0; f < FMH; ++f) \
                afr[f] = *(const bf16x8*)(&LA[DB][ks][abase + mh * MH_OFF + f * 512]); \
            _Pragma("unroll") \
            for (int mi = 0; mi < FMH; ++mi) \
                _Pragma("unroll") \
                for (int ni = 0; ni < FN; ++ni) \
                    acc[mh * FMH + mi][ni] = __builtin_amdgcn_mfma_f32_16x16x32_bf16( \
                        afr[mi], bfr[ni], acc[mh * FMH + mi][ni], 0, 0, 0); \
        } \
    } \
    __builtin_amdgcn_s_setprio(0); \
    __builtin_amdgcn_sched_barrier(0); \
} while (0)

template <int MODE, int BM, int BN, int WM, int WN, int MINW>
__global__ __launch_bounds__(WM * WN * 64, MINW)
void gemm2s(const ushort_t* __restrict__ A, const ushort_t* __restrict__ Bm,
            int N, int K, int grid_m, int grid_n,
            const float* __restrict__ bias,
            float* __restrict__ outF, ushort_t* __restrict__ outB) {
    constexpr int NT   = WM * WN * 64;
    constexpr int FMH  = BM / (32 * WM);
    constexpr int FN   = BN / (16 * WN);
    constexpr int MH_OFF = (BM / WM / 2) * 32;
    constexpr int VMWN = 8 * (BM + BN) / NT;

    __shared__ __align__(16) ushort_t LA[2][2][BM * 32];
    __shared__ __align__(16) ushort_t LB[2][2][BN * 32];

    const int nwg = gridDim.x;
    int bid = blockIdx.x;
    int q = nwg >> 3, r = nwg & 7;
    int xcd = bid & 7, slot = bid >> 3;
    int wg = (xcd < r ? xcd * (q + 1) : r * (q + 1) + (xcd - r) * q) + slot;
    int per_col = (grid_m / 7) * 21;
    int gn = wg / per_col;  int r1 = wg - gn * per_col;
    int gm = r1 / 21;       int ii = r1 - gm * 21;
    int tile_m = gm * 7 + ii / 3;
    int tile_n = gn * 3 + (ii - (ii / 3) * 3);

    const ushort_t* Ab = A  + (size_t)tile_m * BM * K;
    const ushort_t* Bb = Bm + (size_t)tile_n * BN * K;

    const int tid  = threadIdx.x;
    const int lane = tid & 63;
    const int wave = tid >> 6;
    const int wr = wave / WN;
    const int wc = wave % WN;

    const int frow = lane & 15;
    const int fsl  = lane >> 4;
    const int rbase = frow * 32 + ((fsl ^ ((frow >> 1) & 3)) << 3);
    const int abase = wr * ((BM / WM) * 32) + rbase;
    const int bbase = wc * ((BN / WN) * 32) + rbase;

    f32x4 acc[2 * FMH][FN];
    #pragma unroll
    for (int i = 0; i < 2 * FMH; i++)
        #pragma unroll
        for (int j = 0; j < FN; j++)
            acc[i][j] = (f32x4){0.f, 0.f, 0.f, 0.f};

    const int nkt = K >> 6;

    STAGE64T(0, 0)
    for (int tb = 0; tb < (nkt >> 1) - 1; ++tb) {
        STAGE64T(2 * tb + 1, 1)
        VMW_C(VMWN); BAR;
        COMPUTE64(0);
        BAR;
        STAGE64T(2 * tb + 2, 0)
        VMW_C(VMWN); BAR;
        COMPUTE64(1);
        BAR;
    }
    STAGE64T(nkt - 1, 1)
    VMW_C(VMWN); BAR;
    COMPUTE64(0);
    BAR;
    VMW(0); BAR;
    COMPUTE64(1);

    const int fq = lane >> 4;
    #pragma unroll
    for (int mi = 0; mi < 2 * FMH; mi++) {
        #pragma unroll
        for (int ni = 0; ni < FN; ni++) {
            int n = tile_n * BN + wc * (BN / WN) + ni * 16 + frow;
            float bn = bias[n];
            #pragma unroll
            for (int rr = 0; rr < 4; rr++) {
                int m = tile_m * BM + wr * (BM / WM) + mi * 16 + fq * 4 + rr;
                float v = acc[mi][ni][rr];
                if constexpr (MODE == 0) {
                    outB[(size_t)m * N + n] = f2bf(gelu_fast(v + bn));
                } else {
                    int b = m / P_, p = m - b * P_;
                    outF[(size_t)(b * SEQ + NCLS + p) * D_ + n] = v + bn;
                }
            }
        }
    }
}

// ---------------------------------------------------------------------------
// cls-path GEMM: round-3 2-phase double-buffered structure (proven), BK=64.
// (Underfilled-latency regime: dense 5-atom compute w/ masked scatter.)
// ---------------------------------------------------------------------------
template <int ROWS, int NT>
__device__ __forceinline__ void stage64(const ushort_t* __restrict__ gbase, int K,
                                        int k0, ushort_t* lds, int tid) {
    constexpr int LOADS = ROWS * 64 * 2 / (NT * 16);
    #pragma unroll
    for (int l = 0; l < LOADS; ++l) {
        int c = l * NT + tid;
        gload16(gbase + (size_t)(c >> 3) * K + k0 + ((c & 7) << 3),
                lds + (size_t)c * 8);
    }
}

template <int FM, int FN>
__device__ __forceinline__ void compute64c(const ushort_t* sA, const ushort_t* sB,
                                           int arow0, int brow0, int lane,
                                           f32x4 (&acc)[FM][FN]) {
    const int frow = lane & 15;
    const int fcol = (lane >> 4) * 8;
    #pragma unroll
    for (int ks = 0; ks < 2; ++ks) {
        bf16x8 af[FM], bfv[FN];
        #pragma unroll
        for (int mi = 0; mi < FM; ++mi)
            af[mi] = *(const bf16x8*)(sA + (size_t)(arow0 + mi * 16 + frow) * 64 + ks * 32 + fcol);
        #pragma unroll
        for (int ni = 0; ni < FN; ++ni)
            bfv[ni] = *(const bf16x8*)(sB + (size_t)(brow0 + ni * 16 + frow) * 64 + ks * 32 + fcol);
        #pragma unroll
        for (int mi = 0; mi < FM; ++mi)
            #pragma unroll
            for (int ni = 0; ni < FN; ++ni)
                acc[mi][ni] = __builtin_amdgcn_mfma_f32_16x16x32_bf16(
                    af[mi], bfv[ni], acc[mi][ni], 0, 0, 0);
    }
}

// MODE 2: if src[m]==atom: HID = bf16(gelu(acc + bias[atom*H_+n]))
// MODE 3: if dst[m]==atom: out[(b*SEQ+nn)*D_+n] = (acc + bias[atom*D_+n])*wgt[m]
template <int MODE, int BMc, int BNc, int WM, int WN>
__global__ __launch_bounds__(WM * WN * 64, 2)
void gemm2p(const ushort_t* __restrict__ A,
            const ushort_t* __restrict__ Bm,
            int N, int K, int grid_n,
            const float* __restrict__ bias,
            float* __restrict__ outF,
            ushort_t* __restrict__ outB,
            const int* __restrict__ selIdx,
            const float* __restrict__ wgt) {
    constexpr int NT = WM * WN * 64;
    constexpr int FM = BMc / WM / 16;
    constexpr int FN = BNc / WN / 16;

    __shared__ __align__(16) ushort_t A0[BMc * 64], A1[BMc * 64];
    __shared__ __align__(16) ushort_t B0[BNc * 64], B1[BNc * 64];

    const int nwg = gridDim.x;
    int bid = blockIdx.x;
    int q = nwg >> 3, r = nwg & 7;
    int xcd = bid & 7, slot = bid >> 3;
    int wg = (xcd < r ? xcd * (q + 1) : r * (q + 1) + (xcd - r) * q) + slot;
    int tile_m = wg / grid_n;
    int tile_n = wg - tile_m * grid_n;
    const int atom = blockIdx.z;

    const ushort_t* Ab = A  + (size_t)tile_m * BMc * K;
    const ushort_t* Bb = Bm + ((size_t)atom * N + (size_t)tile_n * BNc) * K;

    const int tid  = threadIdx.x;
    const int lane = tid & 63;
    const int wave = tid >> 6;
    const int arow0 = (wave / WN) * (BMc / WM);
    const int brow0 = (wave % WN) * (BNc / WN);

    f32x4 acc[FM][FN];
    #pragma unroll
    for (int i = 0; i < FM; i++)
        #pragma unroll
        for (int j = 0; j < FN; j++)
            acc[i][j] = (f32x4){0.f, 0.f, 0.f, 0.f};

    const int nkt = K >> 6;

    stage64<BMc, NT>(Ab, K, 0, A0, tid);
    stage64<BNc, NT>(Bb, K, 0, B0, tid);
    asm volatile("s_waitcnt vmcnt(0)" ::: "memory");
    __syncthreads();

    for (int t = 0; t < nkt; t += 2) {
        stage64<BMc, NT>(Ab, K, (t + 1) << 6, A1, tid);
        stage64<BNc, NT>(Bb, K, (t + 1) << 6, B1, tid);
        compute64c<FM, FN>(A0, B0, arow0, brow0, lane, acc);
        asm volatile("s_waitcnt vmcnt(0)" ::: "memory");
        __syncthreads();
        if (t + 2 < nkt) {
            stage64<BMc, NT>(Ab, K, (t + 2) << 6, A0, tid);
            stage64<BNc, NT>(Bb, K, (t + 2) << 6, B0, tid);
        }
        compute64c<FM, FN>(A1, B1, arow0, brow0, lane, acc);
        asm volatile("s_waitcnt vmcnt(0)" ::: "memory");
        __syncthreads();
    }

    const int frow = lane & 15;
    const int fq   = lane >> 4;
    #pragma unroll
    for (int mi = 0; mi < FM; mi++) {
        #pragma unroll
        for (int ni = 0; ni < FN; ni++) {
            int n = tile_n * BNc + brow0 + ni * 16 + frow;
            float bn;
            if constexpr (MODE == 2) bn = bias[atom * H_ + n];
            else                     bn = bias[atom * D_ + n];
            #pragma unroll
            for (int rr = 0; rr < 4; rr++) {
                int m = tile_m * BMc + arow0 + mi * 16 + fq * 4 + rr;
                float v = acc[mi][ni][rr];
                if constexpr (MODE == 2) {
                    if (selIdx[m] == atom)
                        outB[(size_t)m * N + n] = f2bf(gelu_fast(v + bn));
                } else { // MODE 3
                    if (selIdx[m] == atom) {
                        int b = m / NCLS, nn = m - b * NCLS;
                        outF[(size_t)(b * SEQ + nn) * D_ + n] = (v + bn) * wgt[m];
                    }
                }
            }
        }
    }
}

// ---------------------------------------------------------------------------
// Launch
// ---------------------------------------------------------------------------
extern "C" void kernel_launch(void* const* d_in, const int* in_sizes, int n_in,
                              void* d_out, int out_size, void* d_ws, size_t ws_size,
                              hipStream_t stream) {
    const float* x   = (const float*)d_in[0];
    const float* w1  = (const float*)d_in[1];
    const float* b1  = (const float*)d_in[2];
    const float* w2  = (const float*)d_in[3];
    const float* b2  = (const float*)d_in[4];
    const float* gd  = (const float*)d_in[5];
    const float* aiw = (const float*)d_in[6];
    const float* aib = (const float*)d_in[7];
    const float* aow = (const float*)d_in[8];
    const float* aob = (const float*)d_in[9];
    float* out = (float*)d_out;

    char* ws = (char*)d_ws;
    ushort_t* Xp   = (ushort_t*)ws; ws += (size_t)NPATCH * D_ * 2;
    ushort_t* W1b  = (ushort_t*)ws; ws += (size_t)H_ * D_ * 2;
    ushort_t* W2b  = (ushort_t*)ws; ws += (size_t)D_ * H_ * 2;
    ushort_t* H1   = (ushort_t*)ws; ws += (size_t)NPATCH * H_ * 2;
    ushort_t* CLSb = (ushort_t*)ws; ws += (size_t)NPAIR * D_ * 2;
    ushort_t* AIWb = (ushort_t*)ws; ws += (size_t)NATOMS * H_ * D_ * 2;
    ushort_t* AOWb = (ushort_t*)ws; ws += (size_t)NATOMS * D_ * H_ * 2;
    ushort_t* HID  = (ushort_t*)ws; ws += (size_t)NPAIR * H_ * 2;
    int*   SRC = (int*)ws;   ws += NPAIR * 4;
    int*   DST = (int*)ws;   ws += NPAIR * 4;
    float* WGT = (float*)ws; ws += NPAIR * 4;

    // prep: all fp32->bf16 conversions + x split in one launch
    prep_kernel<<<PREP_NB, 256, 0, stream>>>(w1, W1b, w2, W2b, aiw, AIWb, aow, AOWb,
                                             x, Xp, CLSb);
    gate_kernel<<<NPAIR, 64, 0, stream>>>(x, gd, SRC, DST, WGT);

    // GEMM0: 128x256 / BK=32 / 8 waves (64x64 wave tile) / 48KB LDS,
    // MINW=4 -> 2 blk/CU (r12's MINW=6 spilled acc; see kernel comment).
    gemm32<0, 128, 256, 2, 4, 4><<<dim3(1176, 1, 1), 512, 0, stream>>>(
        Xp, W1b, H_, D_, 98, 12, b1, nullptr, H1);
    // GEMM1: r9-exact (128x128 / BK=64 / 8 waves / 64KB -> 2 blk/CU, ~105us)
    gemm2s<1, 128, 128, 2, 4, 4><<<dim3(588, 1, 1), 512, 0, stream>>>(
        H1, W2b, D_, H_, 98, 6, b2, out, nullptr);

    // cls path: dense all-atom GEMMs with masked epilogue scatter
    gemm2p<2, 64, 128, 1, 2><<<dim3(NPAIR / 64 * (H_ / 128), 1, NATOMS), 128, 0, stream>>>(
        CLSb, AIWb, H_, D_, H_ / 128, aib, nullptr, HID, SRC, nullptr);
    gemm2p<3, 64, 128, 1, 2><<<dim3(NPAIR / 64 * (D_ / 128), 1, NATOMS), 128, 0, stream>>>(
        HID, AOWb, D_, H_, D_ / 128, aob, out, nullptr, DST, WGT);
}